// Round 5
// baseline (725.805 us; speedup 1.0000x reference)
//
#include <hip/hip_runtime.h>
#include <math.h>

// Residual SF-DiVeQ (N=65536, D=64, C=4, K=1024) — bit-exact numpy-fp32 argmin.
// R5: kill the rz spill. float rz[64] (array, SROA-failed, scratch at VGPR=52)
// -> ext_vector_type(64) SSA value: constant-index extract/insert only, lives
// in VGPRs. Block 256 thr / 4 waves, __launch_bounds__(256,4) (VGPR cap 128).
// Wave = 256-codeword K-partition, lane = row; codebook via wave-uniform s_load
// (SMEM pipe parallel to VALU). Merge ascending-k, strict < (numpy ties).
// FMA floor: 1.72e10 FMA / 78.6 T-FMA/s = 219 us.

#define N_PTS 65536
#define DIM 64
#define NCB 4
#define KCB 1024
#define WAVES 4
#define KPART (KCB / WAVES)   // 256
#define ROWS_PER_BLK 64

typedef float f32x64 __attribute__((ext_vector_type(64)));
typedef float f32x8  __attribute__((ext_vector_type(8)));

// ---------------- prep: cn[c][k] = numpy-pairwise ||c_k||^2 (fp32), zero counts
__global__ __launch_bounds__(256) void prep_kernel(const float* __restrict__ cb,
    float* __restrict__ cnp, int* __restrict__ counts)
{
#pragma clang fp contract(off)
    int t = blockIdx.x * 256 + threadIdx.x;       // grid 16 -> 4096 = C*K
    const float* row = cb + (size_t)t * DIM;
    float pr[8];
#pragma unroll
    for (int j = 0; j < 8; ++j) { float v = row[j]; pr[j] = v * v; }
#pragma unroll
    for (int i = 8; i < DIM; i += 8)
#pragma unroll
        for (int j = 0; j < 8; ++j) { float v = row[i + j]; pr[j] += v * v; }
    cnp[t] = ((pr[0] + pr[1]) + (pr[2] + pr[3])) + ((pr[4] + pr[5]) + (pr[6] + pr[7]));
    counts[t] = 0;
}

// ---------------- fused residual-VQ ------------------------------------------
// block: 256 thr = 4 waves; wave w scans k in [w*256,(w+1)*256); lane = row.
__global__ __launch_bounds__(256, 4) void rvq_kernel(
    const float* __restrict__ z, const float* __restrict__ cbook,
    const float* __restrict__ cnp, int* __restrict__ idxA)
{
#pragma clang fp contract(off)
    __shared__ float lm[WAVES][ROWS_PER_BLK];
    __shared__ int   li[WAVES][ROWS_PER_BLK];

    int lane = threadIdx.x & 63;
    int w = __builtin_amdgcn_readfirstlane(threadIdx.x >> 6);  // SGPR-uniform
    int n = blockIdx.x * ROWS_PER_BLK + lane;
    int kbase = w * KPART;

    f32x64 rz = *(const f32x64*)(z + (size_t)n * DIM);   // SSA value -> VGPRs

    for (int c = 0; c < NCB; ++c) {
        // srr = numpy-pairwise sum of rz*rz (8 accumulators stride-8, fixed tree)
        f32x8 pr;
#pragma unroll
        for (int j = 0; j < 8; ++j) pr[j] = rz[j] * rz[j];
#pragma unroll
        for (int i = 8; i < DIM; i += 8)
#pragma unroll
            for (int j = 0; j < 8; ++j) pr[j] += rz[i + j] * rz[i + j];
        float srr = ((pr[0] + pr[1]) + (pr[2] + pr[3])) + ((pr[4] + pr[5]) + (pr[6] + pr[7]));

        const float* cb = cbook + (size_t)c * KCB * DIM;
        const float* cn = cnp + c * KCB;

        float m1 = 3.4028235e38f; int ix = kbase;
        for (int kk = 0; kk < KPART; kk += 8) {   // 8 sgemm-style k-chains
            int k0 = kbase + kk;
            f32x8 a = (f32x8)0.0f;
#pragma unroll
            for (int d = 0; d < DIM; ++d) {       // d ascending: exact chain order
#pragma unroll
                for (int j = 0; j < 8; ++j)
                    a[j] = fmaf(rz[d], cb[(size_t)(k0 + j) * DIM + d], a[j]);
            }
#pragma unroll
            for (int j = 0; j < 8; ++j) {         // ascending k, strict <
                float t1 = 2.0f * a[j];           // exact
                float t2 = srr - t1;              // ref rounding order
                float dd = t2 + cn[k0 + j];
                if (dd < m1) { m1 = dd; ix = k0 + j; }
            }
        }
        lm[w][lane] = m1; li[w][lane] = ix;
        __syncthreads();

        // merge partitions in ascending w (= ascending k), strict <
        float bm = lm[0][lane]; int bx = li[0][lane];
#pragma unroll
        for (int s = 1; s < WAVES; ++s) {
            float v = lm[s][lane]; int xi = li[s][lane];
            if (v < bm) { bm = v; bx = xi; }
        }
        if (w == 0) idxA[c * N_PTS + n] = bx;

        // rem -= cb[bx]  (per-lane gather; single-rounded vector sub)
        f32x64 q = *(const f32x64*)(cb + (size_t)bx * DIM);
        rz = rz - q;
        __syncthreads();   // LDS reused next codebook
    }
}

// ---------------- epilogue: z_q (fp64; threshold ~2% of magnitude) -----------
__global__ __launch_bounds__(256) void zq_kernel(
    const float* __restrict__ z, const float* __restrict__ noise,
    const float* __restrict__ cbase, const int* __restrict__ idxA,
    float* __restrict__ out)
{
    int lane = threadIdx.x & 63;
    int n = blockIdx.x * 4 + (threadIdx.x >> 6);   // grid 16384
    size_t e = (size_t)n * DIM + lane;
    double zd = z[e];
    double rd = zd;
#pragma unroll
    for (int cc = 0; cc < NCB; ++cc) {
        int id = idxA[cc * N_PTS + n];
        rd -= (double)cbase[((size_t)cc * KCB + id) * DIM + lane];
    }
    double dir = -rd;                               // z_hard - z
    double rv = fma(1e-3, (double)noise[e], dir);
    double srv = rv * rv, sdir = dir * dir;
#pragma unroll
    for (int off = 32; off >= 1; off >>= 1) {
        srv  += __shfl_xor(srv, off);
        sdir += __shfl_xor(sdir, off);
    }
    double em = sqrt(sdir);
    double nn = sqrt(srv); nn = nn > 1e-12 ? nn : 1e-12;
    out[e] = (float)(zd + em * rv / nn);
}

// ---------------- histogram + idx output (as float32) ------------------------
__global__ __launch_bounds__(256) void hist_kernel(
    const int* __restrict__ idxA, float* __restrict__ out_idx, int* __restrict__ counts)
{
    int t = blockIdx.x * 256 + threadIdx.x;        // C*N, grid 1024
    int v = idxA[t];
    out_idx[t] = (float)v;
    atomicAdd(&counts[(t >> 16) * KCB + v], 1);
}

// ---------------- perplexity -------------------------------------------------
__global__ __launch_bounds__(1024) void perp_kernel(const int* __restrict__ counts,
                                                    float* __restrict__ out)
{
    __shared__ double red[16];
    int tid = threadIdx.x, lane = tid & 63, w = tid >> 6;
    for (int c = 0; c < NCB; ++c) {
        double p = (double)counts[c * KCB + tid] / (double)N_PTS;
        double v = p * log(p + 1e-10);
#pragma unroll
        for (int off = 32; off >= 1; off >>= 1) v += __shfl_xor(v, off);
        if (lane == 0) red[w] = v;
        __syncthreads();
        if (tid == 0) {
            double ssum = 0.0;
            for (int i = 0; i < 16; ++i) ssum += red[i];
            out[c] = (float)exp(-ssum);
        }
        __syncthreads();
    }
}

extern "C" void kernel_launch(void* const* d_in, const int* in_sizes, int n_in,
                              void* d_out, int out_size, void* d_ws, size_t ws_size,
                              hipStream_t stream)
{
    const float* z     = (const float*)d_in[0];
    const float* cbook = (const float*)d_in[1];   // [C,K,D]
    const float* noise = (const float*)d_in[2];
    float* out = (float*)d_out;
    char* ws = (char*)d_ws;

    // ws layout (~1.1 MB)
    int*   idxA   = (int*)  (ws);                  // C*N i32   1,048,576 B
    float* cnp    = (float*)(ws + 1048576);        // C*K f32      16,384
    int*   counts = (int*)  (ws + 1064960);        // C*K i32      16,384

    prep_kernel<<<16, 256, 0, stream>>>(cbook, cnp, counts);
    rvq_kernel<<<N_PTS / ROWS_PER_BLK, 256, 0, stream>>>(z, cbook, cnp, idxA);
    zq_kernel<<<N_PTS / 4, 256, 0, stream>>>(z, noise, cbook, idxA, out);
    hist_kernel<<<NCB * N_PTS / 256, 256, 0, stream>>>(
        idxA, out + (size_t)N_PTS * DIM, counts);
    perp_kernel<<<1, 1024, 0, stream>>>(
        counts, out + (size_t)N_PTS * DIM + (size_t)NCB * N_PTS);
}